// Round 1
// baseline (270.381 us; speedup 1.0000x reference)
//
#include <hip/hip_runtime.h>
#include <math.h>

#define NB 4
#define PGT 10000

// ---------------- reduction helpers ----------------
static __device__ __forceinline__ float waveReduceSum(float v) {
#pragma unroll
    for (int o = 32; o; o >>= 1) v += __shfl_down(v, o);
    return v;
}

// Full 256-thread block reduce -> one f64 atomic. Block-uniform call sites only.
static __device__ __forceinline__ void blockAtomicAddD(double* dst, float v, float* red) {
    v = waveReduceSum(v);
    int wid = threadIdx.x >> 6;
    if ((threadIdx.x & 63) == 0) red[wid] = v;
    __syncthreads();
    if (threadIdx.x == 0) atomicAdd(dst, (double)(red[0] + red[1] + red[2] + red[3]));
    __syncthreads();
}

// ---------------- fused main kernel ----------------
// Block ranges:
//   [0,816)     pg : per-wave min+argmin over 10000 GT points, 4 pred pts/wave
//   [816,1296)  gp : per-thread min over all pred points (LDS-tiled), 1 gt pt/thread
//   [1296,1348) laplace + move
//   [1348,1604) BCE image loss
// acc layout (doubles): 0-2 pg, 3-5 gp, 6-8 edge, 9-11 normal, 12-14 lap, 15-17 move, 18 bce
__global__ __launch_bounds__(256) void fused_kernel(
    const float* __restrict__ pc0, const float* __restrict__ pc1, const float* __restrict__ pc2,
    const float* __restrict__ pb0, const float* __restrict__ pb1, const float* __restrict__ pb2,
    const int* __restrict__ lp0, const int* __restrict__ lp1, const int* __restrict__ lp2,
    const float* __restrict__ gtp, const float* __restrict__ gimg, const float* __restrict__ rec,
    double* __restrict__ acc, int* __restrict__ idx0)
{
    __shared__ float4 s_tile[640];
    __shared__ float s_red[4];
    const int b = blockIdx.x;
    const int tid = threadIdx.x;

    if (b < 816) {
        // ----- dist_pg + argmin (argmin kept for batch 0 only) -----
        int level, n, chunk, Pl, loff; const float* P;
        if (b < 40)       { level = 0; Pl = 156;  loff = 0;   P = pc0; n = b / 10;           chunk = b % 10; }
        else if (b < 196) { level = 1; Pl = 618;  loff = 156; P = pc1; int t = b - 40;  n = t / 39;  chunk = t % 39; }
        else              { level = 2; Pl = 2466; loff = 774; P = pc2; int t = b - 196; n = t / 155; chunk = t % 155; }
        const int wave = tid >> 6, lane = tid & 63;
        const int pbase = chunk * 16 + wave * 4;
        const float* pn = P + (size_t)n * Pl * 3;
        float px[4], py[4], pz[4]; bool val[4];
#pragma unroll
        for (int j = 0; j < 4; j++) {
            int pi = pbase + j; val[j] = (pi < Pl); int ps = val[j] ? pi : 0;
            px[j] = pn[ps * 3 + 0]; py[j] = pn[ps * 3 + 1]; pz[j] = pn[ps * 3 + 2];
        }
        float bd[4] = {1e30f, 1e30f, 1e30f, 1e30f}; int bi[4] = {0, 0, 0, 0};
        const float* g = gtp + (size_t)n * PGT * 3;
        for (int q = lane; q < PGT; q += 64) {
            float gx = g[q * 3 + 0], gy = g[q * 3 + 1], gz = g[q * 3 + 2];
#pragma unroll
            for (int j = 0; j < 4; j++) {
                float dx = px[j] - gx, dy = py[j] - gy, dz = pz[j] - gz;
                float d = fmaf(dz, dz, fmaf(dy, dy, dx * dx));
                if (d < bd[j]) { bd[j] = d; bi[j] = q; }
            }
        }
        // cross-lane min with first-occurrence tie-break (matches jnp.argmin)
#pragma unroll
        for (int j = 0; j < 4; j++) {
#pragma unroll
            for (int o = 1; o < 64; o <<= 1) {
                float od = __shfl_xor(bd[j], o);
                int   oi = __shfl_xor(bi[j], o);
                if (od < bd[j] || (od == bd[j] && oi < bi[j])) { bd[j] = od; bi[j] = oi; }
            }
        }
        float contrib = 0.f;
        if (lane == 0) {
#pragma unroll
            for (int j = 0; j < 4; j++) if (val[j]) {
                contrib += bd[j];
                if (n == 0) idx0[loff + pbase + j] = bi[j];
            }
            s_red[wave] = contrib;
        }
        __syncthreads();
        if (tid == 0) atomicAdd(&acc[level], (double)(s_red[0] + s_red[1] + s_red[2] + s_red[3]));
    }
    else if (b < 1296) {
        // ----- dist_gp: one gt point per thread, pred points staged in LDS tiles -----
        int t = b - 816;
        int level = t / 160; int r = t % 160; int n = r / 40; int qc = r % 40;
        int Pl; const float* P;
        if (level == 0)      { Pl = 156;  P = pc0; }
        else if (level == 1) { Pl = 618;  P = pc1; }
        else                 { Pl = 2466; P = pc2; }
        const float* pn = P + (size_t)n * Pl * 3;
        int q = qc * 256 + tid; bool vq = (q < PGT);
        const float* g = gtp + (size_t)n * PGT * 3;
        float qx = 0.f, qy = 0.f, qz = 0.f;
        if (vq) { qx = g[q * 3 + 0]; qy = g[q * 3 + 1]; qz = g[q * 3 + 2]; }
        float bd = 1e30f;
        int ntile = (Pl + 639) / 640;
        for (int tt = 0; tt < ntile; tt++) {
            int tb = tt * 640;
            int tp = Pl - tb; if (tp > 640) tp = 640;
            __syncthreads();
            for (int i = tid; i < tp; i += 256)
                s_tile[i] = make_float4(pn[(tb + i) * 3 + 0], pn[(tb + i) * 3 + 1], pn[(tb + i) * 3 + 2], 0.f);
            __syncthreads();
            for (int p = 0; p < tp; p++) {
                float4 pp = s_tile[p];  // uniform address -> LDS broadcast, no bank conflict
                float dx = pp.x - qx, dy = pp.y - qy, dz = pp.z - qz;
                float d = fmaf(dz, dz, fmaf(dy, dy, dx * dx));
                bd = fminf(bd, d);
            }
        }
        __syncthreads();
        blockAtomicAddD(&acc[3 + level], vq ? bd : 0.f, s_red);
    }
    else if (b < 1348) {
        // ----- laplace + move -----
        int t = b - 1296;
        int level, Pl, bstart; const float* P; const float* B; const int* L;
        if (t < 3)       { level = 0; Pl = 156;  P = pc0; B = pb0; L = lp0; bstart = 0; }
        else if (t < 13) { level = 1; Pl = 618;  P = pc1; B = pb1; L = lp1; bstart = 3; }
        else             { level = 2; Pl = 2466; P = pc2; B = pb2; L = lp2; bstart = 13; }
        int item = (t - bstart) * 256 + tid;
        float lap_s = 0.f, mov_s = 0.f;
        if (item < 4 * Pl) {
            int n = item / Pl, p = item % Pl;
            const int* lr = L + p * 10;
            float cnt = (float)lr[9];                 // lap_idx[:, -1]
            const float* Bn = B + (size_t)n * Pl * 3;
            const float* Pn = P + (size_t)n * Pl * 3;
            float sbx = 0, sby = 0, sbz = 0, spx = 0, spy = 0, spz = 0;
#pragma unroll
            for (int k = 0; k < 8; k++) {             // lap_idx[:, :-2] = cols 0..7
                int id = lr[k];
                if (id >= 0) {
                    sbx += Bn[id * 3 + 0]; sby += Bn[id * 3 + 1]; sbz += Bn[id * 3 + 2];
                    spx += Pn[id * 3 + 0]; spy += Pn[id * 3 + 1]; spz += Pn[id * 3 + 2];
                }
            }
            float bx = Bn[p * 3], by = Bn[p * 3 + 1], bz = Bn[p * 3 + 2];
            float vx = Pn[p * 3], vy = Pn[p * 3 + 1], vz = Pn[p * 3 + 2];
            float dx = (bx - sbx / cnt) - (vx - spx / cnt);
            float dy = (by - sby / cnt) - (vy - spy / cnt);
            float dz = (bz - sbz / cnt) - (vz - spz / cnt);
            lap_s = dx * dx + dy * dy + dz * dz;
            float mx = bx - vx, my = by - vy, mz = bz - vz;
            mov_s = mx * mx + my * my + mz * mz;      // only used for level>0 in finalize
        }
        blockAtomicAddD(&acc[12 + level], lap_s, s_red);
        blockAtomicAddD(&acc[15 + level], mov_s, s_red);
    }
    else {
        // ----- BCE image loss -----
        int t = b - 1348;
        const int N = 602112;
        float s = 0.f;
        for (int i = t * 256 + tid; i < N; i += 256 * 256) {
            float gv = gimg[i], rv = rec[i];
            s -= gv * logf(rv) + (1.f - gv) * logf(1.f - rv);
        }
        blockAtomicAddD(&acc[18], s, s_red);
    }
}

// ---------------- edge + normal (needs batch-0 argmin from fused pg) ----------------
__global__ __launch_bounds__(256) void edge_kernel(
    const float* __restrict__ pc0, const float* __restrict__ pc1, const float* __restrict__ pc2,
    const int* __restrict__ e0, const int* __restrict__ e1, const int* __restrict__ e2,
    const float* __restrict__ gtn, const int* __restrict__ idx0,
    double* __restrict__ acc)
{
    __shared__ float s_red[4];
    int b = blockIdx.x, tid = threadIdx.x;
    int level, El, Pl, loff, bstart; const float* P; const int* E;
    if (b < 8)       { level = 0; El = 462;  Pl = 156;  loff = 0;   bstart = 0;  P = pc0; E = e0; }
    else if (b < 37) { level = 1; El = 1848; Pl = 618;  loff = 156; bstart = 8;  P = pc1; E = e1; }
    else             { level = 2; El = 7392; Pl = 2466; loff = 774; bstart = 37; P = pc2; E = e2; }
    int item = (b - bstart) * 256 + tid;
    float es = 0.f, ns = 0.f;
    if (item < 4 * El) {
        int n = item / El, e = item % El;
        int a = E[e * 2 + 0], b2 = E[e * 2 + 1];
        const float* Pn = P + (size_t)n * Pl * 3;
        float ax = Pn[a * 3], ay = Pn[a * 3 + 1], az = Pn[a * 3 + 2];
        float bx = Pn[b2 * 3], by = Pn[b2 * 3 + 1], bz = Pn[b2 * 3 + 2];
        float ex = ax - bx, ey = ay - by, ez = az - bz;
        float el2 = ex * ex + ey * ey + ez * ez;
        es = el2;                                     // mse(p[a],p[b])*3 == sum(el2)/(4E)
        float einv = 1.f / fmaxf(sqrtf(el2), 1e-12f);
        int ig = idx0[loff + a];                      // idx_pg[0][a] — batch-0 indices
        const float* Nv = gtn + ((size_t)n * PGT + ig) * 3;
        float nx = Nv[0], ny = Nv[1], nz = Nv[2];
        float ninv = 1.f / fmaxf(sqrtf(nx * nx + ny * ny + nz * nz), 1e-12f);
        float dot = (ex * nx + ey * ny + ez * nz) * einv * ninv;
        ns = fabsf(dot);
    }
    blockAtomicAddD(&acc[6 + level], es, s_red);
    blockAtomicAddD(&acc[9 + level], ns, s_red);
}

// ---------------- finalize ----------------
__global__ void final_kernel(const double* __restrict__ acc, float* __restrict__ out) {
    if (threadIdx.x == 0 && blockIdx.x == 0) {
        const double Pn[3] = {156.0, 618.0, 2466.0};
        const double En[3] = {462.0, 1848.0, 7392.0};
        const double lc[3] = {0.2, 1.0, 1.0};
        double chamfer = 0, edge = 0, nrm = 0, lap = 0, mov = 0;
        for (int i = 0; i < 3; i++) {
            chamfer += acc[i] / (4.0 * Pn[i]) + 0.55 * acc[3 + i] / (4.0 * PGT);
            edge += acc[6 + i] / (4.0 * En[i]);
            nrm  += acc[9 + i] / (4.0 * En[i]);
            lap  += lc[i] * acc[12 + i] / (4.0 * Pn[i]);
            if (i > 0) mov += lc[i] * acc[15 + i] / (4.0 * Pn[i]);
        }
        double img = acc[18] / 602112.0;
        double loss = chamfer + img + 0.5 * lap + 0.1 * mov + 0.1 * edge + 0.00016 * nrm;
        out[0] = (float)loss;
    }
}

extern "C" void kernel_launch(void* const* d_in, const int* in_sizes, int n_in,
                              void* d_out, int out_size, void* d_ws, size_t ws_size,
                              hipStream_t stream) {
    const float *pc[3], *pb[3]; const int *ed[3], *lp[3];
    // setup_inputs() dict order interleaves per-level tensors; detect vs signature order.
    bool dict = (n_in >= 2 && in_sizes[1] == in_sizes[0]);
    if (dict) {
        for (int i = 0; i < 3; i++) {
            pc[i] = (const float*)d_in[4 * i + 0];
            pb[i] = (const float*)d_in[4 * i + 1];
            ed[i] = (const int*)  d_in[4 * i + 2];
            lp[i] = (const int*)  d_in[4 * i + 3];
        }
    } else {
        for (int i = 0; i < 3; i++) {
            pc[i] = (const float*)d_in[i];
            pb[i] = (const float*)d_in[3 + i];
            ed[i] = (const int*)  d_in[6 + i];
            lp[i] = (const int*)  d_in[9 + i];
        }
    }
    const float* gtp  = (const float*)d_in[12];
    const float* gtn  = (const float*)d_in[13];
    const float* gimg = (const float*)d_in[14];
    const float* rec  = (const float*)d_in[15];

    double* acc = (double*)d_ws;                       // 19 doubles used
    int* idx0 = (int*)((char*)d_ws + 256);             // 3240 ints (batch-0 argmin per level)

    hipMemsetAsync(d_ws, 0, 256, stream);              // zero accumulators (ws is poisoned)
    fused_kernel<<<1604, 256, 0, stream>>>(pc[0], pc[1], pc[2], pb[0], pb[1], pb[2],
                                           lp[0], lp[1], lp[2], gtp, gimg, rec, acc, idx0);
    edge_kernel<<<153, 256, 0, stream>>>(pc[0], pc[1], pc[2], ed[0], ed[1], ed[2], gtn, idx0, acc);
    final_kernel<<<1, 64, 0, stream>>>(acc, (float*)d_out);
}

// Round 2
// 171.423 us; speedup vs baseline: 1.5773x; 1.5773x over previous
//
#include <hip/hip_runtime.h>
#include <math.h>

#define NB 4
#define PGT 10000

// ws layout:
//   bytes [0,152)    : 19 doubles acc
//   byte  192        : int done-counter
//   bytes [256,13216): idx0 (3240 ints, batch-0 argmin per level)
//   bytes [16384, +480000): gpmin  (3 levels x 4 batch x 10000 uint float-bits)
// acc: 0-2 pg, 3-5 gp, 6-8 edge, 9-11 normal, 12-14 lap, 15-17 move, 18 bce

// ---------------- reduction helpers ----------------
static __device__ __forceinline__ float waveReduceSum(float v) {
#pragma unroll
    for (int o = 32; o; o >>= 1) v += __shfl_down(v, o);
    return v;
}

static __device__ __forceinline__ void blockAtomicAddD(double* dst, float v, float* red) {
    v = waveReduceSum(v);
    int wid = threadIdx.x >> 6;
    if ((threadIdx.x & 63) == 0) red[wid] = v;
    __syncthreads();
    if (threadIdx.x == 0) atomicAdd(dst, (double)(red[0] + red[1] + red[2] + red[3]));
    __syncthreads();
}

// ---------------- fused main kernel ----------------
// Block ranges:
//   [0,816)      pg : per-wave min+argmin over 10000 GT points, 4 pred pts/wave, x2 q-unroll
//   [816,1776)   gp : per-thread partial min over a pred CHUNK (LDS tile, x4 unroll) -> atomicMin
//   [1776,1828)  laplace + move
//   [1828,2084)  BCE image loss
__global__ __launch_bounds__(256) void fused_kernel(
    const float* __restrict__ pc0, const float* __restrict__ pc1, const float* __restrict__ pc2,
    const float* __restrict__ pb0, const float* __restrict__ pb1, const float* __restrict__ pb2,
    const int* __restrict__ lp0, const int* __restrict__ lp1, const int* __restrict__ lp2,
    const float* __restrict__ gtp, const float* __restrict__ gimg, const float* __restrict__ rec,
    double* __restrict__ acc, int* __restrict__ idx0, unsigned* __restrict__ gpmin)
{
    __shared__ float4 s_tile[640];
    __shared__ float s_red[4];
    const int b = blockIdx.x;
    const int tid = threadIdx.x;

    if (b < 816) {
        // ----- dist_pg + argmin (argmin kept for batch 0 only) -----
        int level, n, chunk, Pl, loff; const float* P;
        if (b < 40)       { level = 0; Pl = 156;  loff = 0;   P = pc0; n = b / 10;           chunk = b % 10; }
        else if (b < 196) { level = 1; Pl = 618;  loff = 156; P = pc1; int t = b - 40;  n = t / 39;  chunk = t % 39; }
        else              { level = 2; Pl = 2466; loff = 774; P = pc2; int t = b - 196; n = t / 155; chunk = t % 155; }
        const int wave = tid >> 6, lane = tid & 63;
        const int pbase = chunk * 16 + wave * 4;
        const float* pn = P + (size_t)n * Pl * 3;
        float px[4], py[4], pz[4], p2[4]; bool val[4];
#pragma unroll
        for (int j = 0; j < 4; j++) {
            int pi = pbase + j; val[j] = (pi < Pl); int ps = val[j] ? pi : 0;
            px[j] = pn[ps * 3 + 0]; py[j] = pn[ps * 3 + 1]; pz[j] = pn[ps * 3 + 2];
            p2[j] = fmaf(px[j], px[j], fmaf(py[j], py[j], pz[j] * pz[j]));
        }
        float bd[4] = {3e38f, 3e38f, 3e38f, 3e38f}; int bi[4] = {0, 0, 0, 0};
        const float* g = gtp + (size_t)n * PGT * 3;
        // 9984 = 78 * 128; two independent q's per iteration for load pipelining
        for (int it = 0; it < 78; it++) {
            int qa = it * 128 + lane, qb = qa + 64;
            float ax = g[qa * 3 + 0], ay = g[qa * 3 + 1], az = g[qa * 3 + 2];
            float bx = g[qb * 3 + 0], by = g[qb * 3 + 1], bz = g[qb * 3 + 2];
            float a2 = fmaf(ax, ax, fmaf(ay, ay, az * az));
            float b2 = fmaf(bx, bx, fmaf(by, by, bz * bz));
#pragma unroll
            for (int j = 0; j < 4; j++) {
                float dota = fmaf(px[j], ax, fmaf(py[j], ay, pz[j] * az));
                float da = fmaf(-2.f, dota, p2[j] + a2);
                if (da < bd[j]) { bd[j] = da; bi[j] = qa; }
                float dotb = fmaf(px[j], bx, fmaf(py[j], by, pz[j] * bz));
                float db = fmaf(-2.f, dotb, p2[j] + b2);
                if (db < bd[j]) { bd[j] = db; bi[j] = qb; }
            }
        }
        {   // tail: q in [9984,10000) -> lanes 0..15
            int qt = 9984 + lane;
            if (qt < PGT) {
                float ax = g[qt * 3 + 0], ay = g[qt * 3 + 1], az = g[qt * 3 + 2];
                float a2 = fmaf(ax, ax, fmaf(ay, ay, az * az));
#pragma unroll
                for (int j = 0; j < 4; j++) {
                    float dota = fmaf(px[j], ax, fmaf(py[j], ay, pz[j] * az));
                    float da = fmaf(-2.f, dota, p2[j] + a2);
                    if (da < bd[j]) { bd[j] = da; bi[j] = qt; }
                }
            }
        }
        // cross-lane min with first-occurrence tie-break (matches jnp.argmin)
#pragma unroll
        for (int j = 0; j < 4; j++) {
#pragma unroll
            for (int o = 1; o < 64; o <<= 1) {
                float od = __shfl_xor(bd[j], o);
                int   oi = __shfl_xor(bi[j], o);
                if (od < bd[j] || (od == bd[j] && oi < bi[j])) { bd[j] = od; bi[j] = oi; }
            }
        }
        float contrib = 0.f;
        if (lane == 0) {
#pragma unroll
            for (int j = 0; j < 4; j++) if (val[j]) {
                contrib += bd[j];
                if (n == 0) idx0[loff + pbase + j] = bi[j];
            }
            s_red[wave] = contrib;
        }
        __syncthreads();
        if (tid == 0) atomicAdd(&acc[level], (double)(s_red[0] + s_red[1] + s_red[2] + s_red[3]));
    }
    else if (b < 1776) {
        // ----- dist_gp: per-thread partial min over one pred chunk, atomicMin merge -----
        int t = b - 816;
        int level, Pl, chunk, tr; const float* P;
        if (t < 160)      { level = 0; Pl = 156;  P = pc0; chunk = 0; tr = t; }
        else if (t < 320) { level = 1; Pl = 618;  P = pc1; chunk = 0; tr = t - 160; }
        else              { level = 2; Pl = 2466; P = pc2; int t2 = t - 320; chunk = t2 / 160; tr = t2 % 160; }
        int n = tr / 40, qc = tr % 40;
        int pstart = chunk * 640;
        int tp = Pl - pstart; if (tp > 640) tp = 640;
        const float* pn = P + ((size_t)n * Pl + pstart) * 3;
        for (int i = tid; i < tp; i += 256) {
            float x = pn[i * 3 + 0], y = pn[i * 3 + 1], z = pn[i * 3 + 2];
            s_tile[i] = make_float4(x, y, z, fmaf(x, x, fmaf(y, y, z * z)));
        }
        __syncthreads();
        int q = qc * 256 + tid; bool vq = (q < PGT);
        const float* g = gtp + (size_t)n * PGT * 3;
        float qx = 0.f, qy = 0.f, qz = 0.f;
        if (vq) { qx = g[q * 3 + 0]; qy = g[q * 3 + 1]; qz = g[q * 3 + 2]; }
        float q2 = fmaf(qx, qx, fmaf(qy, qy, qz * qz));
        float bd = 3e38f;
        int p = 0;
        for (; p + 4 <= tp; p += 4) {  // 4 independent broadcast LDS reads in flight
            float4 a0 = s_tile[p], a1 = s_tile[p + 1], a2 = s_tile[p + 2], a3 = s_tile[p + 3];
            float d0 = fmaf(-2.f, fmaf(a0.x, qx, fmaf(a0.y, qy, a0.z * qz)), a0.w + q2);
            float d1 = fmaf(-2.f, fmaf(a1.x, qx, fmaf(a1.y, qy, a1.z * qz)), a1.w + q2);
            float d2 = fmaf(-2.f, fmaf(a2.x, qx, fmaf(a2.y, qy, a2.z * qz)), a2.w + q2);
            float d3 = fmaf(-2.f, fmaf(a3.x, qx, fmaf(a3.y, qy, a3.z * qz)), a3.w + q2);
            bd = fminf(bd, fminf(fminf(d0, d1), fminf(d2, d3)));
        }
        for (; p < tp; p++) {
            float4 a0 = s_tile[p];
            float d0 = fmaf(-2.f, fmaf(a0.x, qx, fmaf(a0.y, qy, a0.z * qz)), a0.w + q2);
            bd = fminf(bd, d0);
        }
        if (vq) {
            // sq-dists >= 0 (clamp fp-noise negatives) -> float bits are uint-monotonic
            atomicMin(&gpmin[(level * 4 + n) * PGT + q], __float_as_uint(fmaxf(bd, 0.f)));
        }
    }
    else if (b < 1828) {
        // ----- laplace + move -----
        int t = b - 1776;
        int level, Pl, bstart; const float* P; const float* B; const int* L;
        if (t < 3)       { level = 0; Pl = 156;  P = pc0; B = pb0; L = lp0; bstart = 0; }
        else if (t < 13) { level = 1; Pl = 618;  P = pc1; B = pb1; L = lp1; bstart = 3; }
        else             { level = 2; Pl = 2466; P = pc2; B = pb2; L = lp2; bstart = 13; }
        int item = (t - bstart) * 256 + tid;
        float lap_s = 0.f, mov_s = 0.f;
        if (item < 4 * Pl) {
            int n = item / Pl, p = item % Pl;
            const int* lr = L + p * 10;
            float cnt = (float)lr[9];
            const float* Bn = B + (size_t)n * Pl * 3;
            const float* Pn = P + (size_t)n * Pl * 3;
            float sbx = 0, sby = 0, sbz = 0, spx = 0, spy = 0, spz = 0;
#pragma unroll
            for (int k = 0; k < 8; k++) {
                int id = lr[k];
                if (id >= 0) {
                    sbx += Bn[id * 3 + 0]; sby += Bn[id * 3 + 1]; sbz += Bn[id * 3 + 2];
                    spx += Pn[id * 3 + 0]; spy += Pn[id * 3 + 1]; spz += Pn[id * 3 + 2];
                }
            }
            float bx = Bn[p * 3], by = Bn[p * 3 + 1], bz = Bn[p * 3 + 2];
            float vx = Pn[p * 3], vy = Pn[p * 3 + 1], vz = Pn[p * 3 + 2];
            float dx = (bx - sbx / cnt) - (vx - spx / cnt);
            float dy = (by - sby / cnt) - (vy - spy / cnt);
            float dz = (bz - sbz / cnt) - (vz - spz / cnt);
            lap_s = dx * dx + dy * dy + dz * dz;
            float mx = bx - vx, my = by - vy, mz = bz - vz;
            mov_s = mx * mx + my * my + mz * mz;
        }
        blockAtomicAddD(&acc[12 + level], lap_s, s_red);
        blockAtomicAddD(&acc[15 + level], mov_s, s_red);
    }
    else {
        // ----- BCE image loss (float4 vectorized) -----
        int t = b - 1828;
        const float4* g4 = (const float4*)gimg;
        const float4* r4 = (const float4*)rec;
        const int N4 = 602112 / 4;  // 150528
        float s = 0.f;
        for (int i = t * 256 + tid; i < N4; i += 256 * 256) {
            float4 gv = g4[i], rv = r4[i];
            s -= gv.x * __logf(rv.x) + (1.f - gv.x) * __logf(1.f - rv.x);
            s -= gv.y * __logf(rv.y) + (1.f - gv.y) * __logf(1.f - rv.y);
            s -= gv.z * __logf(rv.z) + (1.f - gv.z) * __logf(1.f - rv.z);
            s -= gv.w * __logf(rv.w) + (1.f - gv.w) * __logf(1.f - rv.w);
        }
        blockAtomicAddD(&acc[18], s, s_red);
    }
}

// ---------------- edge + normal + gp-reduce + finalize ----------------
// Blocks [0,153): edge+normal.  [153,273): gp-min reduce.  Last finished block finalizes.
__global__ __launch_bounds__(256) void edge_kernel(
    const float* __restrict__ pc0, const float* __restrict__ pc1, const float* __restrict__ pc2,
    const int* __restrict__ e0, const int* __restrict__ e1, const int* __restrict__ e2,
    const float* __restrict__ gtn, const int* __restrict__ idx0,
    const unsigned* __restrict__ gpmin, double* __restrict__ acc,
    unsigned* __restrict__ done, float* __restrict__ out)
{
    __shared__ float s_red[4];
    int b = blockIdx.x, tid = threadIdx.x;
    if (b < 153) {
        int level, El, Pl, loff, bstart; const float* P; const int* E;
        if (b < 8)       { level = 0; El = 462;  Pl = 156;  loff = 0;   bstart = 0;  P = pc0; E = e0; }
        else if (b < 37) { level = 1; El = 1848; Pl = 618;  loff = 156; bstart = 8;  P = pc1; E = e1; }
        else             { level = 2; El = 7392; Pl = 2466; loff = 774; bstart = 37; P = pc2; E = e2; }
        int item = (b - bstart) * 256 + tid;
        float es = 0.f, ns = 0.f;
        if (item < 4 * El) {
            int n = item / El, e = item % El;
            int a = E[e * 2 + 0], b2 = E[e * 2 + 1];
            const float* Pn = P + (size_t)n * Pl * 3;
            float ax = Pn[a * 3], ay = Pn[a * 3 + 1], az = Pn[a * 3 + 2];
            float bx = Pn[b2 * 3], by = Pn[b2 * 3 + 1], bz = Pn[b2 * 3 + 2];
            float ex = ax - bx, ey = ay - by, ez = az - bz;
            float el2 = ex * ex + ey * ey + ez * ez;
            es = el2;
            float einv = 1.f / fmaxf(sqrtf(el2), 1e-12f);
            int ig = idx0[loff + a];
            const float* Nv = gtn + ((size_t)n * PGT + ig) * 3;
            float nx = Nv[0], ny = Nv[1], nz = Nv[2];
            float ninv = 1.f / fmaxf(sqrtf(nx * nx + ny * ny + nz * nz), 1e-12f);
            ns = fabsf((ex * nx + ey * ny + ez * nz) * einv * ninv);
        }
        blockAtomicAddD(&acc[6 + level], es, s_red);
        blockAtomicAddD(&acc[9 + level], ns, s_red);
    } else {
        int r = b - 153;            // [0,120): 40 blocks per level, 1000 entries each
        int level = r / 40, blk = r % 40;
        int base = level * 40000 + blk * 1000;
        float s = 0.f;
        for (int i = tid; i < 1000; i += 256) s += __uint_as_float(gpmin[base + i]);
        blockAtomicAddD(&acc[3 + level], s, s_red);
    }
    // ----- last-done-block finalize -----
    __threadfence();
    if (tid == 0) {
        unsigned old = atomicAdd(done, 1u);
        if (old == gridDim.x - 1) {
            double a[19];
            for (int i = 0; i < 19; i++) a[i] = atomicAdd(&acc[i], 0.0);  // coherent read
            const double Pn[3] = {156.0, 618.0, 2466.0};
            const double En[3] = {462.0, 1848.0, 7392.0};
            const double lc[3] = {0.2, 1.0, 1.0};
            double chamfer = 0, edge = 0, nrm = 0, lap = 0, mov = 0;
            for (int i = 0; i < 3; i++) {
                chamfer += a[i] / (4.0 * Pn[i]) + 0.55 * a[3 + i] / (4.0 * PGT);
                edge += a[6 + i] / (4.0 * En[i]);
                nrm  += a[9 + i] / (4.0 * En[i]);
                lap  += lc[i] * a[12 + i] / (4.0 * Pn[i]);
                if (i > 0) mov += lc[i] * a[15 + i] / (4.0 * Pn[i]);
            }
            double img = a[18] / 602112.0;
            out[0] = (float)(chamfer + img + 0.5 * lap + 0.1 * mov + 0.1 * edge + 0.00016 * nrm);
        }
    }
}

extern "C" void kernel_launch(void* const* d_in, const int* in_sizes, int n_in,
                              void* d_out, int out_size, void* d_ws, size_t ws_size,
                              hipStream_t stream) {
    const float *pc[3], *pb[3]; const int *ed[3], *lp[3];
    bool dict = (n_in >= 2 && in_sizes[1] == in_sizes[0]);   // dict vs signature order
    if (dict) {
        for (int i = 0; i < 3; i++) {
            pc[i] = (const float*)d_in[4 * i + 0];
            pb[i] = (const float*)d_in[4 * i + 1];
            ed[i] = (const int*)  d_in[4 * i + 2];
            lp[i] = (const int*)  d_in[4 * i + 3];
        }
    } else {
        for (int i = 0; i < 3; i++) {
            pc[i] = (const float*)d_in[i];
            pb[i] = (const float*)d_in[3 + i];
            ed[i] = (const int*)  d_in[6 + i];
            lp[i] = (const int*)  d_in[9 + i];
        }
    }
    const float* gtp  = (const float*)d_in[12];
    const float* gtn  = (const float*)d_in[13];
    const float* gimg = (const float*)d_in[14];
    const float* rec  = (const float*)d_in[15];

    double*   acc   = (double*)d_ws;
    unsigned* done  = (unsigned*)((char*)d_ws + 192);
    int*      idx0  = (int*)((char*)d_ws + 256);
    unsigned* gpmin = (unsigned*)((char*)d_ws + 16384);

    hipMemsetAsync(d_ws, 0, 16384, stream);                 // acc + counter + idx0
    hipMemsetAsync(gpmin, 0x7F, 3 * 4 * PGT * 4, stream);   // gpmin = 3.39e38f bits

    fused_kernel<<<2084, 256, 0, stream>>>(pc[0], pc[1], pc[2], pb[0], pb[1], pb[2],
                                           lp[0], lp[1], lp[2], gtp, gimg, rec,
                                           acc, idx0, gpmin);
    edge_kernel<<<273, 256, 0, stream>>>(pc[0], pc[1], pc[2], ed[0], ed[1], ed[2],
                                         gtn, idx0, gpmin, acc, done, (float*)d_out);
}

// Round 3
// 166.288 us; speedup vs baseline: 1.6260x; 1.0309x over previous
//
#include <hip/hip_runtime.h>
#include <math.h>

#define PGT 10000

// ws layout (bytes):
//   [0,4)              done counter          (memset 0x7F -> init 0x7F7F7F7F)
//   [256, 480256)      gpmin  u32[3*4*10000] float-bits (memset 0x7F -> 3.39e38f)
//   [481280, 688640)   pgmin  u64[3240*4*2]  ((distbits<<32)|idx), plain stores
//   [690176, +3984)    partials double[498], pre-scaled, plain stores
// partial slots: lap/move [0,104) bce [104,168) edge [168,321) norm [321,474)
//                pgred [474,486) gpred [486,498)
#define NSLOT 498

static __device__ __forceinline__ float waveReduceSum(float v) {
#pragma unroll
    for (int o = 32; o; o >>= 1) v += __shfl_down(v, o);
    return v;
}
static __device__ __forceinline__ double waveReduceSumD(double v) {
#pragma unroll
    for (int o = 32; o; o >>= 1) v += __shfl_down(v, o);
    return v;
}
// Block-uniform; result valid on ALL threads.
static __device__ __forceinline__ float blockReduceF(float v, float* red) {
    v = waveReduceSum(v);
    __syncthreads();
    if ((threadIdx.x & 63) == 0) red[threadIdx.x >> 6] = v;
    __syncthreads();
    return red[0] + red[1] + red[2] + red[3];
}
static __device__ __forceinline__ double blockReduceD(double v, double* red) {
    v = waveReduceSumD(v);
    __syncthreads();
    if ((threadIdx.x & 63) == 0) red[threadIdx.x >> 6] = v;
    __syncthreads();
    return red[0] + red[1] + red[2] + red[3];
}

// ---------------- K1 ----------------
// [0,1760)    gp : 320-pred LDS chunk x 256 gts -> register min -> atomicMin u32
// [1760,3392) pg : 16 preds x 5000-gt half -> wave min(+idx for n==0) -> u64 store
// [3392,3444) laplace + move -> scaled double partials
// [3444,3508) BCE -> scaled double partials
__global__ __launch_bounds__(256) void k1_kernel(
    const float* __restrict__ pc0, const float* __restrict__ pc1, const float* __restrict__ pc2,
    const float* __restrict__ pb0, const float* __restrict__ pb1, const float* __restrict__ pb2,
    const int* __restrict__ lp0, const int* __restrict__ lp1, const int* __restrict__ lp2,
    const float* __restrict__ gtp, const float* __restrict__ gimg, const float* __restrict__ rec,
    unsigned* __restrict__ gpmin, unsigned long long* __restrict__ pgmin,
    double* __restrict__ part)
{
    __shared__ float4 s_tile[320];
    __shared__ float s_red[4];
    const int b = blockIdx.x;
    const int tid = threadIdx.x;

    if (b < 1760) {
        // ----- gp chunks -----
        int g = b / 160, tr = b % 160;
        int level, Pl, pstart; const float* P;
        if (g == 0)     { level = 0; Pl = 156;  P = pc0; pstart = 0; }
        else if (g < 3) { level = 1; Pl = 618;  P = pc1; pstart = (g - 1) * 320; }
        else            { level = 2; Pl = 2466; P = pc2; pstart = (g - 3) * 320; }
        int n = tr / 40, qc = tr % 40;
        int tp = Pl - pstart; if (tp > 320) tp = 320;
        const float* pn = P + ((size_t)n * Pl + pstart) * 3;
        for (int i = tid; i < tp; i += 256) {
            float x = pn[i * 3 + 0], y = pn[i * 3 + 1], z = pn[i * 3 + 2];
            s_tile[i] = make_float4(x, y, z, fmaf(x, x, fmaf(y, y, z * z)));
        }
        __syncthreads();
        int q = qc * 256 + tid; bool vq = (q < PGT);
        const float* g3 = gtp + (size_t)n * PGT * 3;
        float qx = 0.f, qy = 0.f, qz = 0.f;
        if (vq) { qx = g3[q * 3 + 0]; qy = g3[q * 3 + 1]; qz = g3[q * 3 + 2]; }
        float q2 = fmaf(qx, qx, fmaf(qy, qy, qz * qz));
        float bd = 3e38f;
        int p = 0;
        for (; p + 4 <= tp; p += 4) {
            float4 a0 = s_tile[p], a1 = s_tile[p + 1], a2 = s_tile[p + 2], a3 = s_tile[p + 3];
            float d0 = fmaf(-2.f, fmaf(a0.x, qx, fmaf(a0.y, qy, a0.z * qz)), a0.w + q2);
            float d1 = fmaf(-2.f, fmaf(a1.x, qx, fmaf(a1.y, qy, a1.z * qz)), a1.w + q2);
            float d2 = fmaf(-2.f, fmaf(a2.x, qx, fmaf(a2.y, qy, a2.z * qz)), a2.w + q2);
            float d3 = fmaf(-2.f, fmaf(a3.x, qx, fmaf(a3.y, qy, a3.z * qz)), a3.w + q2);
            bd = fminf(bd, fminf(fminf(d0, d1), fminf(d2, d3)));
        }
        for (; p < tp; p++) {
            float4 a0 = s_tile[p];
            bd = fminf(bd, fmaf(-2.f, fmaf(a0.x, qx, fmaf(a0.y, qy, a0.z * qz)), a0.w + q2));
        }
        if (vq) atomicMin(&gpmin[(level * 4 + n) * PGT + q], __float_as_uint(fmaxf(bd, 0.f)));
    }
    else if (b < 3392) {
        // ----- pg: q-half h of [0,10000) -----
        int t = b - 1760;
        int h = t & 1, t2 = t >> 1;
        int level, n, chunk, Pl, loff; const float* P;
        if (t2 < 40)       { level = 0; Pl = 156;  loff = 0;   P = pc0; n = t2 / 10;          chunk = t2 % 10; }
        else if (t2 < 196) { level = 1; Pl = 618;  loff = 156; P = pc1; int u = t2 - 40;  n = u / 39;  chunk = u % 39; }
        else               { level = 2; Pl = 2466; loff = 774; P = pc2; int u = t2 - 196; n = u / 155; chunk = u % 155; }
        const int wave = tid >> 6, lane = tid & 63;
        const int pbase = chunk * 16 + wave * 4;
        const float* pn = P + (size_t)n * Pl * 3;
        float px[4], py[4], pz[4], p2[4]; bool val[4];
#pragma unroll
        for (int j = 0; j < 4; j++) {
            int pi = pbase + j; val[j] = (pi < Pl); int ps = val[j] ? pi : 0;
            px[j] = pn[ps * 3 + 0]; py[j] = pn[ps * 3 + 1]; pz[j] = pn[ps * 3 + 2];
            p2[j] = fmaf(px[j], px[j], fmaf(py[j], py[j], pz[j] * pz[j]));
        }
        const float* g3 = gtp + (size_t)n * PGT * 3;
        const int qbeg = h * 5000, qend = qbeg + 5000;
        if (n == 0) {
            float bd[4] = {3e38f, 3e38f, 3e38f, 3e38f}; int bi[4] = {0, 0, 0, 0};
            int q0 = qbeg;
            for (; q0 + 128 <= qend; q0 += 128) {
                int qa = q0 + lane, qb = qa + 64;
                float ax = g3[qa * 3], ay = g3[qa * 3 + 1], az = g3[qa * 3 + 2];
                float bx = g3[qb * 3], by = g3[qb * 3 + 1], bz = g3[qb * 3 + 2];
                float a2 = fmaf(ax, ax, fmaf(ay, ay, az * az));
                float b2 = fmaf(bx, bx, fmaf(by, by, bz * bz));
#pragma unroll
                for (int j = 0; j < 4; j++) {
                    float da = fmaf(-2.f, fmaf(px[j], ax, fmaf(py[j], ay, pz[j] * az)), p2[j] + a2);
                    if (da < bd[j]) { bd[j] = da; bi[j] = qa; }
                    float db = fmaf(-2.f, fmaf(px[j], bx, fmaf(py[j], by, pz[j] * bz)), p2[j] + b2);
                    if (db < bd[j]) { bd[j] = db; bi[j] = qb; }
                }
            }
            for (; q0 < qend; q0 += 64) {
                int qt = q0 + lane;
                if (qt < qend) {
                    float ax = g3[qt * 3], ay = g3[qt * 3 + 1], az = g3[qt * 3 + 2];
                    float a2 = fmaf(ax, ax, fmaf(ay, ay, az * az));
#pragma unroll
                    for (int j = 0; j < 4; j++) {
                        float da = fmaf(-2.f, fmaf(px[j], ax, fmaf(py[j], ay, pz[j] * az)), p2[j] + a2);
                        if (da < bd[j]) { bd[j] = da; bi[j] = qt; }
                    }
                }
            }
#pragma unroll
            for (int j = 0; j < 4; j++) {
#pragma unroll
                for (int o = 1; o < 64; o <<= 1) {
                    float od = __shfl_xor(bd[j], o);
                    int   oi = __shfl_xor(bi[j], o);
                    if (od < bd[j] || (od == bd[j] && oi < bi[j])) { bd[j] = od; bi[j] = oi; }
                }
            }
            if (lane == 0) {
#pragma unroll
                for (int j = 0; j < 4; j++) if (val[j])
                    pgmin[(size_t)(loff + pbase + j) * 2 + h] =
                        ((unsigned long long)__float_as_uint(bd[j]) << 32) | (unsigned)bi[j];
            }
        } else {
            float bd[4] = {3e38f, 3e38f, 3e38f, 3e38f};
            int q0 = qbeg;
            for (; q0 + 128 <= qend; q0 += 128) {
                int qa = q0 + lane, qb = qa + 64;
                float ax = g3[qa * 3], ay = g3[qa * 3 + 1], az = g3[qa * 3 + 2];
                float bx = g3[qb * 3], by = g3[qb * 3 + 1], bz = g3[qb * 3 + 2];
                float a2 = fmaf(ax, ax, fmaf(ay, ay, az * az));
                float b2 = fmaf(bx, bx, fmaf(by, by, bz * bz));
#pragma unroll
                for (int j = 0; j < 4; j++) {
                    float da = fmaf(-2.f, fmaf(px[j], ax, fmaf(py[j], ay, pz[j] * az)), p2[j] + a2);
                    float db = fmaf(-2.f, fmaf(px[j], bx, fmaf(py[j], by, pz[j] * bz)), p2[j] + b2);
                    bd[j] = fminf(bd[j], fminf(da, db));
                }
            }
            for (; q0 < qend; q0 += 64) {
                int qt = q0 + lane;
                if (qt < qend) {
                    float ax = g3[qt * 3], ay = g3[qt * 3 + 1], az = g3[qt * 3 + 2];
                    float a2 = fmaf(ax, ax, fmaf(ay, ay, az * az));
#pragma unroll
                    for (int j = 0; j < 4; j++)
                        bd[j] = fminf(bd[j], fmaf(-2.f, fmaf(px[j], ax, fmaf(py[j], ay, pz[j] * az)), p2[j] + a2));
                }
            }
#pragma unroll
            for (int j = 0; j < 4; j++) {
#pragma unroll
                for (int o = 1; o < 64; o <<= 1) bd[j] = fminf(bd[j], __shfl_xor(bd[j], o));
            }
            if (lane == 0) {
#pragma unroll
                for (int j = 0; j < 4; j++) if (val[j])
                    pgmin[((size_t)(n * 3240 + loff + pbase + j)) * 2 + h] =
                        ((unsigned long long)__float_as_uint(bd[j]) << 32);
            }
        }
    }
    else if (b < 3444) {
        // ----- laplace + move -----
        int t = b - 3392;
        int level, Pl, bstart; const float* P; const float* B; const int* L;
        if (t < 3)       { level = 0; Pl = 156;  P = pc0; B = pb0; L = lp0; bstart = 0; }
        else if (t < 13) { level = 1; Pl = 618;  P = pc1; B = pb1; L = lp1; bstart = 3; }
        else             { level = 2; Pl = 2466; P = pc2; B = pb2; L = lp2; bstart = 13; }
        int item = (t - bstart) * 256 + tid;
        float lap_s = 0.f, mov_s = 0.f;
        if (item < 4 * Pl) {
            int n = item / Pl, p = item % Pl;
            const int* lr = L + p * 10;
            float cnt = (float)lr[9];
            const float* Bn = B + (size_t)n * Pl * 3;
            const float* Pn = P + (size_t)n * Pl * 3;
            float sbx = 0, sby = 0, sbz = 0, spx = 0, spy = 0, spz = 0;
#pragma unroll
            for (int k = 0; k < 8; k++) {
                int id = lr[k];
                if (id >= 0) {
                    sbx += Bn[id * 3 + 0]; sby += Bn[id * 3 + 1]; sbz += Bn[id * 3 + 2];
                    spx += Pn[id * 3 + 0]; spy += Pn[id * 3 + 1]; spz += Pn[id * 3 + 2];
                }
            }
            float bx = Bn[p * 3], by = Bn[p * 3 + 1], bz = Bn[p * 3 + 2];
            float vx = Pn[p * 3], vy = Pn[p * 3 + 1], vz = Pn[p * 3 + 2];
            float dx = (bx - sbx / cnt) - (vx - spx / cnt);
            float dy = (by - sby / cnt) - (vy - spy / cnt);
            float dz = (bz - sbz / cnt) - (vz - spz / cnt);
            lap_s = dx * dx + dy * dy + dz * dz;
            float mx = bx - vx, my = by - vy, mz = bz - vz;
            mov_s = mx * mx + my * my + mz * mz;
        }
        float lsum = blockReduceF(lap_s, s_red);
        float msum = blockReduceF(mov_s, s_red);
        if (tid == 0) {
            const double lc[3] = {0.2, 1.0, 1.0};
            double inv = 1.0 / (4.0 * (double)Pl);
            part[2 * t]     = (double)lsum * (0.5 * lc[level] * inv);
            part[2 * t + 1] = (level > 0) ? (double)msum * (0.1 * lc[level] * inv) : 0.0;
        }
    }
    else {
        // ----- BCE -----
        int t = b - 3444;
        const float4* g4 = (const float4*)gimg;
        const float4* r4 = (const float4*)rec;
        const int N4 = 602112 / 4;
        float s = 0.f;
        for (int i = t * 256 + tid; i < N4; i += 64 * 256) {
            float4 gv = g4[i], rv = r4[i];
            s -= gv.x * __logf(rv.x) + (1.f - gv.x) * __logf(1.f - rv.x);
            s -= gv.y * __logf(rv.y) + (1.f - gv.y) * __logf(1.f - rv.y);
            s -= gv.z * __logf(rv.z) + (1.f - gv.z) * __logf(1.f - rv.z);
            s -= gv.w * __logf(rv.w) + (1.f - gv.w) * __logf(1.f - rv.w);
        }
        float sum = blockReduceF(s, s_red);
        if (tid == 0) part[104 + t] = (double)sum / 602112.0;
    }
}

// ---------------- K2: edge+normal, pg/gp reduce, finalize ----------------
__global__ __launch_bounds__(256) void k2_kernel(
    const float* __restrict__ pc0, const float* __restrict__ pc1, const float* __restrict__ pc2,
    const int* __restrict__ e0, const int* __restrict__ e1, const int* __restrict__ e2,
    const float* __restrict__ gtn,
    const unsigned long long* __restrict__ pgmin, const unsigned* __restrict__ gpmin,
    double* __restrict__ part, unsigned* __restrict__ done, float* __restrict__ out)
{
    __shared__ float s_red[4];
    __shared__ double s_redd[4];
    __shared__ int s_flag;
    const int b = blockIdx.x, tid = threadIdx.x;
    if (b < 153) {
        int level, El, Pl, loff, bstart; const float* P; const int* E;
        if (b < 8)       { level = 0; El = 462;  Pl = 156;  loff = 0;   bstart = 0;  P = pc0; E = e0; }
        else if (b < 37) { level = 1; El = 1848; Pl = 618;  loff = 156; bstart = 8;  P = pc1; E = e1; }
        else             { level = 2; El = 7392; Pl = 2466; loff = 774; bstart = 37; P = pc2; E = e2; }
        int item = (b - bstart) * 256 + tid;
        float es = 0.f, ns = 0.f;
        if (item < 4 * El) {
            int n = item / El, e = item % El;
            int a = E[e * 2 + 0], b2 = E[e * 2 + 1];
            const float* Pn = P + (size_t)n * Pl * 3;
            float ax = Pn[a * 3], ay = Pn[a * 3 + 1], az = Pn[a * 3 + 2];
            float bx = Pn[b2 * 3], by = Pn[b2 * 3 + 1], bz = Pn[b2 * 3 + 2];
            float ex = ax - bx, ey = ay - by, ez = az - bz;
            float el2 = ex * ex + ey * ey + ez * ez;
            es = el2;
            float einv = 1.f / fmaxf(sqrtf(el2), 1e-12f);
            unsigned long long k0 = pgmin[(size_t)(loff + a) * 2];
            unsigned long long k1 = pgmin[(size_t)(loff + a) * 2 + 1];
            unsigned long long k = k0 < k1 ? k0 : k1;      // min dist, min idx tiebreak
            int ig = (int)(k & 0xFFFFFFFFull);
            const float* Nv = gtn + ((size_t)n * PGT + ig) * 3;
            float nx = Nv[0], ny = Nv[1], nz = Nv[2];
            float ninv = 1.f / fmaxf(sqrtf(nx * nx + ny * ny + nz * nz), 1e-12f);
            ns = fabsf((ex * nx + ey * ny + ez * nz) * einv * ninv);
        }
        float esum = blockReduceF(es, s_red);
        float nsum = blockReduceF(ns, s_red);
        if (tid == 0) {
            double inv = 1.0 / (4.0 * (double)El);
            part[168 + b] = (double)esum * (0.1 * inv);
            part[321 + b] = (double)nsum * (0.00016 * inv);
        }
    } else if (b < 165) {
        int i = b - 153, level = i >> 2, n = i & 3;
        int Pl = (level == 0) ? 156 : (level == 1) ? 618 : 2466;
        int loff = (level == 0) ? 0 : (level == 1) ? 156 : 774;
        double s = 0.0;
        for (int p = tid; p < Pl; p += 256) {
            size_t base = (size_t)(n * 3240 + loff + p) * 2;
            unsigned long long k0 = pgmin[base], k1 = pgmin[base + 1];
            unsigned long long k = k0 < k1 ? k0 : k1;
            s += (double)__uint_as_float((unsigned)(k >> 32));
        }
        s = blockReduceD(s, s_redd);
        if (tid == 0) part[474 + i] = s / (4.0 * (double)Pl);
    } else {
        int i = b - 165, level = i >> 2, n = i & 3;
        const unsigned* gm = gpmin + (size_t)(level * 4 + n) * PGT;
        double s = 0.0;
        for (int q = tid; q < PGT; q += 256) s += (double)__uint_as_float(gm[q]);
        s = blockReduceD(s, s_redd);
        if (tid == 0) part[486 + i] = s * (0.55 / (4.0 * (double)PGT));
    }
    // ----- last-done finalize -----
    __threadfence();
    if (tid == 0) {
        unsigned old = atomicAdd(done, 1u);
        s_flag = (old == 0x7F7F7F7Fu + 176u) ? 1 : 0;
        __threadfence();
    }
    __syncthreads();
    if (s_flag) {
        double s = 0.0;
        for (int i = tid; i < NSLOT; i += 256) s += part[i];
        s = blockReduceD(s, s_redd);
        if (tid == 0) out[0] = (float)s;
    }
}

extern "C" void kernel_launch(void* const* d_in, const int* in_sizes, int n_in,
                              void* d_out, int out_size, void* d_ws, size_t ws_size,
                              hipStream_t stream) {
    const float *pc[3], *pb[3]; const int *ed[3], *lp[3];
    bool dict = (n_in >= 2 && in_sizes[1] == in_sizes[0]);   // dict vs signature order
    if (dict) {
        for (int i = 0; i < 3; i++) {
            pc[i] = (const float*)d_in[4 * i + 0];
            pb[i] = (const float*)d_in[4 * i + 1];
            ed[i] = (const int*)  d_in[4 * i + 2];
            lp[i] = (const int*)  d_in[4 * i + 3];
        }
    } else {
        for (int i = 0; i < 3; i++) {
            pc[i] = (const float*)d_in[i];
            pb[i] = (const float*)d_in[3 + i];
            ed[i] = (const int*)  d_in[6 + i];
            lp[i] = (const int*)  d_in[9 + i];
        }
    }
    const float* gtp  = (const float*)d_in[12];
    const float* gtn  = (const float*)d_in[13];
    const float* gimg = (const float*)d_in[14];
    const float* rec  = (const float*)d_in[15];

    unsigned*           done  = (unsigned*)d_ws;
    unsigned*           gpmin = (unsigned*)((char*)d_ws + 256);
    unsigned long long* pgmin = (unsigned long long*)((char*)d_ws + 481280);
    double*             part  = (double*)((char*)d_ws + 690176);

    // one memset: done (-> 0x7F7F7F7F, known init) + gpmin (-> 3.39e38f bits)
    hipMemsetAsync(d_ws, 0x7F, 480256, stream);

    k1_kernel<<<3508, 256, 0, stream>>>(pc[0], pc[1], pc[2], pb[0], pb[1], pb[2],
                                        lp[0], lp[1], lp[2], gtp, gimg, rec,
                                        gpmin, pgmin, part);
    k2_kernel<<<177, 256, 0, stream>>>(pc[0], pc[1], pc[2], ed[0], ed[1], ed[2],
                                       gtn, pgmin, gpmin, part, done, (float*)d_out);
}